// Round 21
// baseline (550.627 us; speedup 1.0000x reference)
//
#include <hip/hip_runtime.h>
#include <cstdint>

#define NUM_CLASSES 20
#define KSEL 5
#define M_PTS 10000
#define C_DIM 256
#define HW 16384
#define NQB 64           // queries per block (grid 512 -> 2 blocks/CU)
#define NJB 64           // j rows per tile
#define NT 158           // 158*64 = 10112 >= 10000
#define MPAD 10112
#define INFV 1e30f

// ws layout (bytes)
#define WS_MN_OFF 0                      // float mn[10112]          = 40448 B
#define WS_MW_OFF 40448u                 // ushort mw[10000*256]     = 5120000 B
#define WS_XB_OFF 5160448u               // ushort xb[32768*256]     = 16777216 B
#define WS_TOTAL  21937664u

typedef short short8 __attribute__((ext_vector_type(8)));
typedef float f32x4 __attribute__((ext_vector_type(4)));

#define MFMA16(a, b, c) __builtin_amdgcn_mfma_f32_16x16x32_bf16(a, b, c, 0, 0, 0)

__device__ __forceinline__ uint pk2(float a, float b) {   // RNE f32->bf16 pair
  uint ua = __float_as_uint(a), ub = __float_as_uint(b);
  ua = (ua + 0x7fffu + ((ua >> 16) & 1u)) >> 16;
  ub = (ub + 0x7fffu + ((ub >> 16) & 1u)) >> 16;
  return (ua & 0xffffu) | (ub << 16);
}

__device__ __forceinline__ void gl16(const ushort* g, ushort* l) {
  __builtin_amdgcn_global_load_lds(
      (const __attribute__((address_space(1))) uint*)g,
      (__attribute__((address_space(3))) uint*)l, 16, 0, 0);
}

// T3/T4 primitives (R17/R18-verified): counted vmcnt + raw s_barrier, no drains.
#define VMCNT5() do { asm volatile("s_waitcnt vmcnt(5)" ::: "memory"); \
                      __builtin_amdgcn_sched_barrier(0); } while (0)
#define VMCNT1() do { asm volatile("s_waitcnt vmcnt(1)" ::: "memory"); \
                      __builtin_amdgcn_sched_barrier(0); } while (0)
#define RAWBAR() do { asm volatile("s_barrier" ::: "memory"); \
                      __builtin_amdgcn_sched_barrier(0); } while (0)

// ---- prep 1: m -> bf16 rows + fp32 norms (INF for padded rows) ----
__global__ void conv_m(const float* __restrict__ mx, ushort* __restrict__ mw,
                       float* __restrict__ mn) {
  const int t = threadIdx.x;
  const int r = blockIdx.x * 64 + (t >> 2);
  const int sg = t & 3;
  if (r >= MPAD) return;
  if (r >= M_PTS) { if (sg == 0) mn[r] = INFV; return; }
  const float4* src = (const float4*)(mx + (size_t)r * C_DIM + sg * 64);
  float4 v[16];
#pragma unroll
  for (int k = 0; k < 16; ++k) v[k] = src[k];
  uint u[32];
  float np = 0.f;
#pragma unroll
  for (int k = 0; k < 16; ++k) {
    u[2 * k]     = pk2(v[k].x, v[k].y);
    u[2 * k + 1] = pk2(v[k].z, v[k].w);
    np = fmaf(v[k].x, v[k].x, np); np = fmaf(v[k].y, v[k].y, np);
    np = fmaf(v[k].z, v[k].z, np); np = fmaf(v[k].w, v[k].w, np);
  }
  uint4* dst = (uint4*)(mw + (size_t)r * C_DIM + sg * 64);
#pragma unroll
  for (int i = 0; i < 8; ++i) dst[i] = *(const uint4*)&u[4 * i];
  np += __shfl_xor(np, 1);
  np += __shfl_xor(np, 2);
  if (sg == 0) mn[r] = np;
}

// ---- prep 2: x[b][c][hw] -> xb[n][c] bf16 (n = b*16384 + hw) ----
__global__ void conv_x(const float* __restrict__ x, ushort* __restrict__ xb) {
  const int t = threadIdx.x;
  const int n = blockIdx.x * 64 + (t & 63);
  const int seg = t >> 6;                      // c range [seg*64, seg*64+64)
  const int bb = n >> 14, hw = n & (HW - 1);
  const float* src = x + (size_t)bb * C_DIM * HW + hw;
  uint u[32];
#pragma unroll 8
  for (int k = 0; k < 32; ++k) {
    const int c = seg * 64 + 2 * k;
    const float a0 = src[(size_t)c * HW];      // coalesced across lanes
    const float a1 = src[(size_t)(c + 1) * HW];
    u[k] = pk2(a0, a1);
  }
  uint4* dst = (uint4*)(xb + (size_t)n * C_DIM + seg * 64);
#pragma unroll
  for (int i = 0; i < 8; ++i) dst[i] = *(const uint4*)&u[4 * i];
}

// ---- main: 512 blocks x 512 thr -> 2 blocks/CU (16 waves/CU, 4/SIMD).
// R18 protocol (counted-vmcnt pipeline, verified twice) + FRAGMENT-ORDER LDS:
// the tile is stored as 32 regions of 1KB, region rg=(wjg*8+ks); within a
// region, lane l's A-fragment sits at byte l*16. Compute reads are therefore
// 64-lane CONTIGUOUS 1KB ds_read_b128 (2-way floor, zero conflicts, SGPR base
// + imm offset per ks). Staging keeps linear LDS dests (rule 21); the
// permutation moves to the per-lane GLOBAL source address:
//   region (wjg,ks), lane l: mw[(j0+wjg*16+lr)*256 + ks*32 + lg*8]
// (lanes {lr,lr+16,lr+32,lr+48} cover one 64B line -> L2-friendly).
// Per tile: mn load / vmcnt(5) / s_barrier / 8 ds_read + 16 MFMA /
// s_barrier / STAGE(t+2) / selection. Last tile vmcnt(1).
__global__ __launch_bounds__(512, 4) void knn_big(
    const float* __restrict__ x, const float* __restrict__ mx,
    const ushort* __restrict__ mw, const float* __restrict__ mn,
    const ushort* __restrict__ xb, const int* __restrict__ my,
    float* __restrict__ out)
{
  __shared__ union {
    ushort AsF[2][32 * 512];                                      // 64 KB
    struct { float Lv[16][KSEL][NQB]; int Lj[16][KSEL][NQB]; } e; // 40 KB overlay
  } sm;

  const int t  = threadIdx.x;
  const int w  = t >> 6;
  const int l  = t & 63;
  const int wj = w >> 1;        // row block: wj*16 .. +16
  const int wq = w & 1;         // col block: wq*32 .. +32
  const int lr = l & 15;
  const int lg = l >> 4;

  const int q0  = blockIdx.x * NQB;
  const int bb  = q0 >> 14;
  const int hw0 = q0 & (HW - 1);

  // ---- B fragments in registers: 2 qf x 8 ks, loaded once ----
  short8 bq[2][8];
#pragma unroll
  for (int qf = 0; qf < 2; ++qf) {
    const ushort* xrow = xb + (size_t)(q0 + wq * 32 + qf * 16 + lr) * C_DIM;
#pragma unroll
    for (int ks = 0; ks < 8; ++ks)
      bq[qf][ks] = *(const short8*)(xrow + ks * 32 + lg * 8);
  }

  float lv[2][KSEL]; int lj[2][KSEL];
#pragma unroll
  for (int qf = 0; qf < 2; ++qf)
#pragma unroll
    for (int e = 0; e < KSEL; ++e) { lv[qf][e] = INFV; lj[qf][e] = 0x7fffffff; }

  // per-lane global source base for staging: + (row-block)*256 + ks*32 added per region
  const ushort* gsrc = mw + (size_t)lr * C_DIM + lg * 8;

  // STAGE: wave w fills regions 4w..4w+3 of buf (each 1KB, linear dest).
#define STAGE(J0S, BUF) do {                                                  \
    _Pragma("unroll")                                                         \
    for (int i_ = 0; i_ < 4; ++i_) {                                          \
      const int rg_  = 4 * w + i_;                                            \
      const int wjg_ = rg_ >> 3, ks_ = rg_ & 7;                               \
      int jr_ = (J0S) + wjg_ * 16 + lr; if (jr_ >= M_PTS) jr_ = M_PTS - 1;    \
      gl16(mw + (size_t)jr_ * C_DIM + ks_ * 32 + lg * 8,                      \
           &sm.AsF[BUF][rg_ * 512]);                                          \
    }                                                                         \
  } while (0)

  // prologue: tiles 0 and 1 in flight (8 gl_lds outstanding)
  STAGE(0, 0);
  STAGE(NJB, 1);

  for (int jt = 0; jt < NT; ++jt) {
    const int j0 = jt * NJB;
    const int buf = jt & 1;

    // mn(t): 1 f32x4 load; compiler inserts its own counted wait before use
    const f32x4 mn4 = *(const f32x4*)(mn + j0 + wj * 16 + 4 * lg);

    if (jt < NT - 1) { VMCNT5(); }   // own tile-t stages retired (in-order)
    else            { VMCNT1(); }    // final tile: only stage(t).4 + mn.1 left
    RAWBAR();                        // all waves' tile-t stages landed

    f32x4 acc[2];
    acc[0] = (f32x4){0.f, 0.f, 0.f, 0.f};
    acc[1] = (f32x4){0.f, 0.f, 0.f, 0.f};

    // lane-linear conflict-free reads: base + ks*1024B + l*16B
    const ushort* tb = &sm.AsF[buf][(wj * 8) * 512 + l * 8];
#pragma unroll
    for (int ks = 0; ks < 8; ++ks) {
      const short8 af0 = *(const short8*)(tb + ks * 512);
      acc[0] = MFMA16(af0, bq[0][ks], acc[0]);
      acc[1] = MFMA16(af0, bq[1][ks], acc[1]);
    }

    RAWBAR();                        // all waves done reading buf -> WAR-safe
    if (jt + 2 < NT) STAGE((jt + 2) * NJB, buf);   // refill 2 ahead

    // selection: score = ||m||^2 - 2*dot. Clamped/padded rows carry mn=1e30 ->
    // never inserted. Ascending-j + strict '<' == top_k lower-index tie-break.
    const int jb = j0 + wj * 16 + 4 * lg;
#pragma unroll
    for (int qf = 0; qf < 2; ++qf) {
#pragma unroll
      for (int e = 0; e < 4; ++e) {
        const float sc = fmaf(-2.f, acc[qf][e], mn4[e]);
        if (sc < lv[qf][4]) {
          const int jg = jb + e;
          const float v0 = lv[qf][0], v1 = lv[qf][1], v2 = lv[qf][2], v3 = lv[qf][3];
          const int   i0 = lj[qf][0], i1 = lj[qf][1], i2 = lj[qf][2], i3 = lj[qf][3];
          const bool c0 = sc < v0, c1 = sc < v1, c2 = sc < v2, c3 = sc < v3;
          lv[qf][4] = c3 ? v3 : sc;             lj[qf][4] = c3 ? i3 : jg;
          lv[qf][3] = c3 ? (c2 ? v2 : sc) : v3; lj[qf][3] = c3 ? (c2 ? i2 : jg) : i3;
          lv[qf][2] = c2 ? (c1 ? v1 : sc) : v2; lj[qf][2] = c2 ? (c1 ? i1 : jg) : i2;
          lv[qf][1] = c1 ? (c0 ? v0 : sc) : v1; lj[qf][1] = c1 ? (c0 ? i0 : jg) : i1;
          lv[qf][0] = c0 ? sc : v0;             lj[qf][0] = c0 ? jg : i0;
        }
      }
    }
  }
#undef STAGE
  (void)gsrc;

  // ---- epilogue (R12/R18-proven): 16 lists/query ([s][e][q], q innermost),
  // merge -> top-8, fp64 re-rank, vote, one-hot write ----
  __syncthreads();                        // full drain + sync -> overlay safe
  {
    const int s = wj * 4 + lg;            // list slot (lg owns rows 4lg..4lg+3)
#pragma unroll
    for (int qf = 0; qf < 2; ++qf) {
      const int q = wq * 32 + qf * 16 + lr;
#pragma unroll
      for (int e = 0; e < KSEL; ++e) { sm.e.Lv[s][e][q] = lv[qf][e]; sm.e.Lj[s][e][q] = lj[qf][e]; }
    }
  }
  __syncthreads();

  if (t < NQB) {                          // thread t finalizes query q0 + t
    float bv[8]; int bj2[8];
#pragma unroll
    for (int k = 0; k < 8; ++k) { bv[k] = INFV; bj2[k] = 0x7fffffff; }
    for (int s = 0; s < 16; ++s) {
#pragma unroll
      for (int e = 0; e < KSEL; ++e) {
        const float v = sm.e.Lv[s][e][t];
        const int  j = sm.e.Lj[s][e][t];
        if (v < bv[7] || (v == bv[7] && j < bj2[7])) {
          int pos = 7;
          while (pos > 0 && (bv[pos - 1] > v || (bv[pos - 1] == v && bj2[pos - 1] > j))) {
            bv[pos] = bv[pos - 1]; bj2[pos] = bj2[pos - 1]; --pos;
          }
          bv[pos] = v; bj2[pos] = j;
        }
      }
    }
    const float *m0 = mx + (size_t)bj2[0] * C_DIM, *m1 = mx + (size_t)bj2[1] * C_DIM;
    const float *m2 = mx + (size_t)bj2[2] * C_DIM, *m3 = mx + (size_t)bj2[3] * C_DIM;
    const float *m4 = mx + (size_t)bj2[4] * C_DIM, *m5 = mx + (size_t)bj2[5] * C_DIM;
    const float *m6 = mx + (size_t)bj2[6] * C_DIM, *m7 = mx + (size_t)bj2[7] * C_DIM;
    const float* xq = x + (size_t)bb * C_DIM * HW + hw0 + t;
    double d0 = 0, d1 = 0, d2 = 0, d3 = 0, d4 = 0, d5 = 0, d6 = 0, d7 = 0;
#pragma unroll 4
    for (int c = 0; c < C_DIM; ++c) {
      const double xv = (double)xq[(size_t)c * HW];
      double dd;
      dd = xv - (double)m0[c]; d0 = fma(dd, dd, d0);
      dd = xv - (double)m1[c]; d1 = fma(dd, dd, d1);
      dd = xv - (double)m2[c]; d2 = fma(dd, dd, d2);
      dd = xv - (double)m3[c]; d3 = fma(dd, dd, d3);
      dd = xv - (double)m4[c]; d4 = fma(dd, dd, d4);
      dd = xv - (double)m5[c]; d5 = fma(dd, dd, d5);
      dd = xv - (double)m6[c]; d6 = fma(dd, dd, d6);
      dd = xv - (double)m7[c]; d7 = fma(dd, dd, d7);
    }
    const double dv[8] = {d0, d1, d2, d3, d4, d5, d6, d7};
    const int    jvv[8] = {bj2[0], bj2[1], bj2[2], bj2[3], bj2[4], bj2[5], bj2[6], bj2[7]};
    int labs[KSEL]; unsigned used = 0;
#pragma unroll
    for (int n = 0; n < KSEL; ++n) {
      double bd = 1e300; int bj = 0x7fffffff; int bk = 0;
#pragma unroll
      for (int k = 0; k < 8; ++k) {
        const bool avail = ((used >> k) & 1u) == 0u;
        if (avail && (dv[k] < bd || (dv[k] == bd && jvv[k] < bj))) {
          bd = dv[k]; bj = jvv[k]; bk = k;
        }
      }
      used |= (1u << bk);
      labs[n] = my[bj];
    }
    int bestLab = NUM_CLASSES, bestCnt = 0;
#pragma unroll
    for (int a = 0; a < KSEL; ++a) {
      int cnt = 0;
#pragma unroll
      for (int b2 = 0; b2 < KSEL; ++b2) cnt += (labs[b2] == labs[a]) ? 1 : 0;
      if (cnt > bestCnt || (cnt == bestCnt && labs[a] < bestLab)) {
        bestCnt = cnt; bestLab = labs[a];
      }
    }
    float* ob = out + (size_t)bb * NUM_CLASSES * HW + hw0 + t;
#pragma unroll
    for (int cls = 0; cls < NUM_CLASSES; ++cls)
      ob[(size_t)cls * HW] = (cls == bestLab) ? 1.0f : 0.0f;   // coalesced per plane
  }
}

// ================= fallback (round-6 kernel, proven): used if ws too small ========
#define FNQB 64
#define FNJB 128
#define FNT 79
#define FXP 264
#define FMP 40
__global__ __launch_bounds__(256, 2) void knn_fb(
    const float* __restrict__ x, const float* __restrict__ mx,
    const int* __restrict__ my, float* __restrict__ out)
{
  __shared__ union {
    struct { ushort xs[FNQB][FXP]; ushort ms[FNJB][FMP]; float mnv[FNJB]; } m;
    struct { float Lv[FNQB][8][KSEL]; int Lj[FNQB][8][KSEL]; } e;
  } sm;
  const int t = threadIdx.x, w = t >> 6, l = t & 63;
  const int wj = w >> 1, wq = w & 1, lr = l & 15, lg = l >> 4;
  const int qflat = blockIdx.x * FNQB, bb = qflat >> 14, hw0 = qflat & (HW - 1);
  const float* xbase = x + (size_t)bb * C_DIM * HW + hw0;
  {
    const int q = t & 63, cpb = t >> 6;
#pragma unroll 8
    for (int k = 0; k < 32; ++k) {
      const int cp = cpb + 4 * k;
      ((uint*)&sm.m.xs[q][0])[cp] =
          pk2(xbase[(size_t)(2 * cp) * HW + q], xbase[(size_t)(2 * cp + 1) * HW + q]);
    }
  }
  float lv[2][KSEL]; int lj[2][KSEL]; float thr[2];
#pragma unroll
  for (int qf = 0; qf < 2; ++qf) {
    thr[qf] = INFV;
#pragma unroll
    for (int e = 0; e < KSEL; ++e) { lv[qf][e] = INFV; lj[qf][e] = 0x7fffffff; }
  }
  const int srow = t >> 1, sh = t & 1;
  for (int jt = 0; jt < FNT; ++jt) {
    const int j0 = jt * FNJB;
    f32x4 acc[4][2];
#pragma unroll
    for (int jf = 0; jf < 4; ++jf)
#pragma unroll
      for (int qf = 0; qf < 2; ++qf) acc[jf][qf] = (f32x4){0.f, 0.f, 0.f, 0.f};
    float np = 0.f;
    for (int ks = 0; ks < 8; ++ks) {
      int jr = j0 + srow; jr = (jr < M_PTS) ? jr : (M_PTS - 1);
      const float4* src = (const float4*)(mx + (size_t)jr * C_DIM + ks * 32 + sh * 16);
      const float4 v0 = src[0], v1 = src[1], v2 = src[2], v3 = src[3];
      __syncthreads();
      uint* dst = (uint*)&sm.m.ms[srow][sh * 16];
      dst[0] = pk2(v0.x, v0.y); dst[1] = pk2(v0.z, v0.w);
      dst[2] = pk2(v1.x, v1.y); dst[3] = pk2(v1.z, v1.w);
      dst[4] = pk2(v2.x, v2.y); dst[5] = pk2(v2.z, v2.w);
      dst[6] = pk2(v3.x, v3.y); dst[7] = pk2(v3.z, v3.w);
      np = fmaf(v0.x, v0.x, np); np = fmaf(v0.y, v0.y, np);
      np = fmaf(v0.z, v0.z, np); np = fmaf(v0.w, v0.w, np);
      np = fmaf(v1.x, v1.x, np); np = fmaf(v1.y, v1.y, np);
      np = fmaf(v1.z, v1.z, np); np = fmaf(v1.w, v1.w, np);
      np = fmaf(v2.x, v2.x, np); np = fmaf(v2.y, v2.y, np);
      np = fmaf(v2.z, v2.z, np); np = fmaf(v2.w, v2.w, np);
      np = fmaf(v3.x, v3.x, np); np = fmaf(v3.y, v3.y, np);
      np = fmaf(v3.z, v3.z, np); np = fmaf(v3.w, v3.w, np);
      if (ks == 7) {
        const float full = np + __shfl_xor(np, 1);
        if (sh == 0) sm.m.mnv[srow] = full;
      }
      __syncthreads();
      const short8 bq0 = *(const short8*)&sm.m.xs[wq * 32 + lr][ks * 32 + 8 * lg];
      const short8 bq1 = *(const short8*)&sm.m.xs[wq * 32 + 16 + lr][ks * 32 + 8 * lg];
#pragma unroll
      for (int jf = 0; jf < 4; ++jf) {
        const short8 af = *(const short8*)&sm.m.ms[wj * 64 + jf * 16 + lr][8 * lg];
        acc[jf][0] = MFMA16(af, bq0, acc[jf][0]);
        acc[jf][1] = MFMA16(af, bq1, acc[jf][1]);
      }
    }
#pragma unroll
    for (int jf = 0; jf < 4; ++jf) {
      const f32x4 mn4 = *(const f32x4*)&sm.m.mnv[wj * 64 + jf * 16 + 4 * lg];
      const int jb = j0 + wj * 64 + jf * 16 + 4 * lg;
#pragma unroll
      for (int qf = 0; qf < 2; ++qf) {
#pragma unroll
        for (int e = 0; e < 4; ++e) {
          const int jg = jb + e;
          const float sc = fmaf(-2.f, acc[jf][qf][e], mn4[e]);
          if (jg < M_PTS && sc < thr[qf]) {
            const float v0 = lv[qf][0], v1 = lv[qf][1], v2 = lv[qf][2], v3 = lv[qf][3];
            const int   i0 = lj[qf][0], i1 = lj[qf][1], i2 = lj[qf][2], i3 = lj[qf][3];
            const bool c0 = sc < v0, c1 = sc < v1, c2 = sc < v2, c3 = sc < v3;
            lv[qf][4] = c3 ? v3 : sc;             lj[qf][4] = c3 ? i3 : jg;
            lv[qf][3] = c3 ? (c2 ? v2 : sc) : v3; lj[qf][3] = c3 ? (c2 ? i2 : jg) : i3;
            lv[qf][2] = c2 ? (c1 ? v1 : sc) : v2; lj[qf][2] = c2 ? (c1 ? i1 : jg) : i2;
            lv[qf][1] = c1 ? (c0 ? v0 : sc) : v1; lj[qf][1] = c1 ? (c0 ? i0 : jg) : i1;
            lv[qf][0] = c0 ? sc : v0;             lj[qf][0] = c0 ? jg : i0;
            thr[qf] = lv[qf][4];
          }
        }
      }
    }
  }
  __syncthreads();
#pragma unroll
  for (int qf = 0; qf < 2; ++qf) {
    const int q = wq * 32 + qf * 16 + lr, s = wj * 4 + lg;
#pragma unroll
    for (int e = 0; e < KSEL; ++e) { sm.e.Lv[q][s][e] = lv[qf][e]; sm.e.Lj[q][s][e] = lj[qf][e]; }
  }
  __syncthreads();
  if (t < FNQB) {
    float bv[8]; int bj2[8];
#pragma unroll
    for (int k = 0; k < 8; ++k) { bv[k] = INFV; bj2[k] = 0x7fffffff; }
    for (int s = 0; s < 8; ++s) {
#pragma unroll
      for (int e = 0; e < KSEL; ++e) {
        const float v = sm.e.Lv[t][s][e]; const int j = sm.e.Lj[t][s][e];
        if (v < bv[7] || (v == bv[7] && j < bj2[7])) {
          int pos = 7;
          while (pos > 0 && (bv[pos - 1] > v || (bv[pos - 1] == v && bj2[pos - 1] > j))) {
            bv[pos] = bv[pos - 1]; bj2[pos] = bj2[pos - 1]; --pos;
          }
          bv[pos] = v; bj2[pos] = j;
        }
      }
    }
    const float *m0 = mx + (size_t)bj2[0] * C_DIM, *m1 = mx + (size_t)bj2[1] * C_DIM;
    const float *m2 = mx + (size_t)bj2[2] * C_DIM, *m3 = mx + (size_t)bj2[3] * C_DIM;
    const float *m4 = mx + (size_t)bj2[4] * C_DIM, *m5 = mx + (size_t)bj2[5] * C_DIM;
    const float *m6 = mx + (size_t)bj2[6] * C_DIM, *m7 = mx + (size_t)bj2[7] * C_DIM;
    const float* xq = xbase + t;
    double d0 = 0, d1 = 0, d2 = 0, d3 = 0, d4 = 0, d5 = 0, d6 = 0, d7 = 0;
#pragma unroll 4
    for (int c = 0; c < C_DIM; ++c) {
      const double xv = (double)xq[(size_t)c * HW];
      double dd;
      dd = xv - (double)m0[c]; d0 = fma(dd, dd, d0);
      dd = xv - (double)m1[c]; d1 = fma(dd, dd, d1);
      dd = xv - (double)m2[c]; d2 = fma(dd, dd, d2);
      dd = xv - (double)m3[c]; d3 = fma(dd, dd, d3);
      dd = xv - (double)m4[c]; d4 = fma(dd, dd, d4);
      dd = xv - (double)m5[c]; d5 = fma(dd, dd, d5);
      dd = xv - (double)m6[c]; d6 = fma(dd, dd, d6);
      dd = xv - (double)m7[c]; d7 = fma(dd, dd, d7);
    }
    const double dv[8] = {d0, d1, d2, d3, d4, d5, d6, d7};
    const int jvv[8] = {bj2[0], bj2[1], bj2[2], bj2[3], bj2[4], bj2[5], bj2[6], bj2[7]};
    int labs[KSEL]; unsigned used = 0;
#pragma unroll
    for (int n = 0; n < KSEL; ++n) {
      double bd = 1e300; int bj = 0x7fffffff; int bk = 0;
#pragma unroll
      for (int k = 0; k < 8; ++k) {
        const bool avail = ((used >> k) & 1u) == 0u;
        if (avail && (dv[k] < bd || (dv[k] == bd && jvv[k] < bj))) {
          bd = dv[k]; bj = jvv[k]; bk = k;
        }
      }
      used |= (1u << bk);
      labs[n] = my[bj];
    }
    int bestLab = NUM_CLASSES, bestCnt = 0;
#pragma unroll
    for (int a = 0; a < KSEL; ++a) {
      int cnt = 0;
#pragma unroll
      for (int b2 = 0; b2 < KSEL; ++b2) cnt += (labs[b2] == labs[a]) ? 1 : 0;
      if (cnt > bestCnt || (cnt == bestCnt && labs[a] < bestLab)) { bestCnt = cnt; bestLab = labs[a]; }
    }
    float* ob = out + (size_t)bb * NUM_CLASSES * HW + hw0 + t;
#pragma unroll
    for (int cls = 0; cls < NUM_CLASSES; ++cls)
      ob[(size_t)cls * HW] = (cls == bestLab) ? 1.0f : 0.0f;
  }
}

extern "C" void kernel_launch(void* const* d_in, const int* in_sizes, int n_in,
                              void* d_out, int out_size, void* d_ws, size_t ws_size,
                              hipStream_t stream) {
  (void)in_sizes; (void)n_in; (void)out_size;
  const float* x  = (const float*)d_in[0];
  const float* mx = (const float*)d_in[2];   // d_in[1] (y) unused by reference
  const int*   my = (const int*)d_in[3];
  float* out = (float*)d_out;
  if (ws_size >= (size_t)WS_TOTAL) {
    float*  mn = (float*)((char*)d_ws + WS_MN_OFF);
    ushort* mw = (ushort*)((char*)d_ws + WS_MW_OFF);
    ushort* xb = (ushort*)((char*)d_ws + WS_XB_OFF);
    conv_m<<<MPAD / 64, 256, 0, stream>>>(mx, mw, mn);
    conv_x<<<32768 / 64, 256, 0, stream>>>(x, xb);
    knn_big<<<32768 / NQB, 512, 0, stream>>>(x, mx, mw, mn, xb, my, out);
  } else {
    knn_fb<<<32768 / FNQB, 256, 0, stream>>>(x, mx, my, out);
  }
}

// Round 22
// 449.570 us; speedup vs baseline: 1.2248x; 1.2248x over previous
//
#include <hip/hip_runtime.h>
#include <cstdint>

#define NUM_CLASSES 20
#define KSEL 5
#define M_PTS 10000
#define C_DIM 256
#define HW 16384
#define NQB 64           // queries per block (grid 512 -> 2 blocks/CU)
#define NJB 64           // j rows per tile
#define NT 158           // 158*64 = 10112 >= 10000
#define MPAD 10112
#define INFV 1e30f

// ws layout (bytes)
#define WS_MN_OFF 0                      // float mn[10112]          = 40448 B
#define WS_MW_OFF 40448u                 // ushort mw[10000*256]     = 5120000 B
#define WS_XB_OFF 5160448u               // ushort xb[32768*256]     = 16777216 B
#define WS_TOTAL  21937664u

typedef short short8 __attribute__((ext_vector_type(8)));
typedef float f32x4 __attribute__((ext_vector_type(4)));

#define MFMA16(a, b, c) __builtin_amdgcn_mfma_f32_16x16x32_bf16(a, b, c, 0, 0, 0)

__device__ __forceinline__ uint pk2(float a, float b) {   // RNE f32->bf16 pair
  uint ua = __float_as_uint(a), ub = __float_as_uint(b);
  ua = (ua + 0x7fffu + ((ua >> 16) & 1u)) >> 16;
  ub = (ub + 0x7fffu + ((ub >> 16) & 1u)) >> 16;
  return (ua & 0xffffu) | (ub << 16);
}

__device__ __forceinline__ void gl16(const ushort* g, ushort* l) {
  __builtin_amdgcn_global_load_lds(
      (const __attribute__((address_space(1))) uint*)g,
      (__attribute__((address_space(3))) uint*)l, 16, 0, 0);
}

// T3/T4 primitives (R17-verified): counted vmcnt + raw s_barrier, no drains.
#define VMCNT5() do { asm volatile("s_waitcnt vmcnt(5)" ::: "memory"); \
                      __builtin_amdgcn_sched_barrier(0); } while (0)
#define VMCNT1() do { asm volatile("s_waitcnt vmcnt(1)" ::: "memory"); \
                      __builtin_amdgcn_sched_barrier(0); } while (0)
#define RAWBAR() do { asm volatile("s_barrier" ::: "memory"); \
                      __builtin_amdgcn_sched_barrier(0); } while (0)

// ---- prep 1: m -> bf16 rows + fp32 norms (INF for padded rows) ----
__global__ void conv_m(const float* __restrict__ mx, ushort* __restrict__ mw,
                       float* __restrict__ mn) {
  const int t = threadIdx.x;
  const int r = blockIdx.x * 64 + (t >> 2);
  const int sg = t & 3;
  if (r >= MPAD) return;
  if (r >= M_PTS) { if (sg == 0) mn[r] = INFV; return; }
  const float4* src = (const float4*)(mx + (size_t)r * C_DIM + sg * 64);
  float4 v[16];
#pragma unroll
  for (int k = 0; k < 16; ++k) v[k] = src[k];
  uint u[32];
  float np = 0.f;
#pragma unroll
  for (int k = 0; k < 16; ++k) {
    u[2 * k]     = pk2(v[k].x, v[k].y);
    u[2 * k + 1] = pk2(v[k].z, v[k].w);
    np = fmaf(v[k].x, v[k].x, np); np = fmaf(v[k].y, v[k].y, np);
    np = fmaf(v[k].z, v[k].z, np); np = fmaf(v[k].w, v[k].w, np);
  }
  uint4* dst = (uint4*)(mw + (size_t)r * C_DIM + sg * 64);
#pragma unroll
  for (int i = 0; i < 8; ++i) dst[i] = *(const uint4*)&u[4 * i];
  np += __shfl_xor(np, 1);
  np += __shfl_xor(np, 2);
  if (sg == 0) mn[r] = np;
}

// ---- prep 2: x[b][c][hw] -> xb[n][c] bf16 (n = b*16384 + hw) ----
__global__ void conv_x(const float* __restrict__ x, ushort* __restrict__ xb) {
  const int t = threadIdx.x;
  const int n = blockIdx.x * 64 + (t & 63);
  const int seg = t >> 6;                      // c range [seg*64, seg*64+64)
  const int bb = n >> 14, hw = n & (HW - 1);
  const float* src = x + (size_t)bb * C_DIM * HW + hw;
  uint u[32];
#pragma unroll 8
  for (int k = 0; k < 32; ++k) {
    const int c = seg * 64 + 2 * k;
    const float a0 = src[(size_t)c * HW];      // coalesced across lanes
    const float a1 = src[(size_t)(c + 1) * HW];
    u[k] = pk2(a0, a1);
  }
  uint4* dst = (uint4*)(xb + (size_t)n * C_DIM + seg * 64);
#pragma unroll
  for (int i = 0; i < 8; ++i) dst[i] = *(const uint4*)&u[4 * i];
}

// ---- main: 512 blocks x 512 thr -> 2 blocks/CU (16 waves/CU, 4/SIMD).
// R12's occupancy shape x R17's verified counted-vmcnt pipeline (= R18 best).
// Wave (wj 0..3, wq 0..1): rows wj*16..+16, cols wq*32..+32. Per tile:
//   issue mn(t) (1 load)
//   s_waitcnt vmcnt(5)   -- own tile-t stages retired (5 = t+1.gl4 + t.mn1)
//   s_barrier            -- all waves' tile-t stages landed
//   8 ds_read_b128 + 16 MFMA on buf[t&1]
//   s_barrier            -- all reads done -> WAR-safe
//   issue 4 gl_lds for tile t+2 into buf[t&1]
//   selection            -- hides issue latency
// Last tile uses vmcnt(1) (only 5 outstanding -> vmcnt(5) would be a no-op).
__global__ __launch_bounds__(512, 4) void knn_big(
    const float* __restrict__ x, const float* __restrict__ mx,
    const ushort* __restrict__ mw, const float* __restrict__ mn,
    const ushort* __restrict__ xb, const int* __restrict__ my,
    float* __restrict__ out)
{
  __shared__ union {
    ushort As[2][NJB][C_DIM];                                     // 64 KB
    struct { float Lv[16][KSEL][NQB]; int Lj[16][KSEL][NQB]; } e; // 40 KB overlay
  } sm;

  const int t  = threadIdx.x;
  const int w  = t >> 6;
  const int l  = t & 63;
  const int wj = w >> 1;        // row block: wj*16 .. +16
  const int wq = w & 1;         // col block: wq*32 .. +32
  const int lr = l & 15;
  const int lg = l >> 4;

  const int q0  = blockIdx.x * NQB;
  const int bb  = q0 >> 14;
  const int hw0 = q0 & (HW - 1);

  // ---- B fragments in registers: 2 qf x 8 ks, loaded once ----
  short8 bq[2][8];
#pragma unroll
  for (int qf = 0; qf < 2; ++qf) {
    const ushort* xrow = xb + (size_t)(q0 + wq * 32 + qf * 16 + lr) * C_DIM;
#pragma unroll
    for (int ks = 0; ks < 8; ++ks)
      bq[qf][ks] = *(const short8*)(xrow + ks * 32 + lg * 8);
  }

  float lv[2][KSEL]; int lj[2][KSEL];
#pragma unroll
  for (int qf = 0; qf < 2; ++qf)
#pragma unroll
    for (int e = 0; e < KSEL; ++e) { lv[qf][e] = INFV; lj[qf][e] = 0x7fffffff; }

  const int s_s    = l & 31;    // staging slot within a row-pair
  const int s_rsub = l >> 5;    // 0/1: which row of the pair

  const int br0 = wj * 16 + lr;           // A-frag row (tile-local, 0..63)
  const int xr  = lr & 7;                 // XOR key (16 = 0 mod 8)

#define STAGE(J0S, BUF) do {                                                  \
    _Pragma("unroll")                                                         \
    for (int i_ = 0; i_ < 4; ++i_) {      /* wave w stages rows w*8..+8 */    \
      const int row_ = w * 8 + 2 * i_ + s_rsub;                               \
      int jr_ = (J0S) + row_; if (jr_ >= M_PTS) jr_ = M_PTS - 1;              \
      gl16(mw + (size_t)jr_ * C_DIM + ((s_s ^ (row_ & 7)) * 8),               \
           &sm.As[BUF][w * 8 + 2 * i_][0]);                                   \
    }                                                                         \
  } while (0)

  // prologue: tiles 0 and 1 in flight (8 gl_lds outstanding)
  STAGE(0, 0);
  STAGE(NJB, 1);

  for (int jt = 0; jt < NT; ++jt) {
    const int j0 = jt * NJB;
    const int buf = jt & 1;

    // mn(t): 1 f32x4 load; compiler inserts its own counted wait before use
    const f32x4 mn4 = *(const f32x4*)(mn + j0 + wj * 16 + 4 * lg);

    if (jt < NT - 1) { VMCNT5(); }   // own tile-t stages retired (in-order)
    else            { VMCNT1(); }    // final tile: only stage(t).4 + mn.1 left
    RAWBAR();                        // all waves' tile-t stages landed

    f32x4 acc[2];
    acc[0] = (f32x4){0.f, 0.f, 0.f, 0.f};
    acc[1] = (f32x4){0.f, 0.f, 0.f, 0.f};

#pragma unroll
    for (int ks = 0; ks < 8; ++ks) {
      const int k0 = ks * 4 + lg;
      const short8 af0 = *(const short8*)&sm.As[buf][br0][(k0 ^ xr) * 8];
      acc[0] = MFMA16(af0, bq[0][ks], acc[0]);
      acc[1] = MFMA16(af0, bq[1][ks], acc[1]);
    }

    RAWBAR();                        // all waves done reading buf -> WAR-safe
    if (jt + 2 < NT) STAGE((jt + 2) * NJB, buf);   // refill 2 ahead

    // selection: score = ||m||^2 - 2*dot. Clamped/padded rows carry mn=1e30 ->
    // never inserted. Ascending-j + strict '<' == top_k lower-index tie-break.
    const int jb = j0 + wj * 16 + 4 * lg;
#pragma unroll
    for (int qf = 0; qf < 2; ++qf) {
#pragma unroll
      for (int e = 0; e < 4; ++e) {
        const float sc = fmaf(-2.f, acc[qf][e], mn4[e]);
        if (sc < lv[qf][4]) {
          const int jg = jb + e;
          const float v0 = lv[qf][0], v1 = lv[qf][1], v2 = lv[qf][2], v3 = lv[qf][3];
          const int   i0 = lj[qf][0], i1 = lj[qf][1], i2 = lj[qf][2], i3 = lj[qf][3];
          const bool c0 = sc < v0, c1 = sc < v1, c2 = sc < v2, c3 = sc < v3;
          lv[qf][4] = c3 ? v3 : sc;             lj[qf][4] = c3 ? i3 : jg;
          lv[qf][3] = c3 ? (c2 ? v2 : sc) : v3; lj[qf][3] = c3 ? (c2 ? i2 : jg) : i3;
          lv[qf][2] = c2 ? (c1 ? v1 : sc) : v2; lj[qf][2] = c2 ? (c1 ? i1 : jg) : i2;
          lv[qf][1] = c1 ? (c0 ? v0 : sc) : v1; lj[qf][1] = c1 ? (c0 ? i0 : jg) : i1;
          lv[qf][0] = c0 ? sc : v0;             lj[qf][0] = c0 ? jg : i0;
        }
      }
    }
  }
#undef STAGE

  // ---- epilogue (R12-proven): 16 lists/query ([s][e][q], q innermost),
  // merge -> top-8, fp64 re-rank, vote, one-hot write ----
  __syncthreads();                        // full drain + sync -> overlay safe
  {
    const int s = wj * 4 + lg;            // list slot (lg owns rows 4lg..4lg+3)
#pragma unroll
    for (int qf = 0; qf < 2; ++qf) {
      const int q = wq * 32 + qf * 16 + lr;
#pragma unroll
      for (int e = 0; e < KSEL; ++e) { sm.e.Lv[s][e][q] = lv[qf][e]; sm.e.Lj[s][e][q] = lj[qf][e]; }
    }
  }
  __syncthreads();

  if (t < NQB) {                          // thread t finalizes query q0 + t
    float bv[8]; int bj2[8];
#pragma unroll
    for (int k = 0; k < 8; ++k) { bv[k] = INFV; bj2[k] = 0x7fffffff; }
    for (int s = 0; s < 16; ++s) {
#pragma unroll
      for (int e = 0; e < KSEL; ++e) {
        const float v = sm.e.Lv[s][e][t];
        const int  j = sm.e.Lj[s][e][t];
        if (v < bv[7] || (v == bv[7] && j < bj2[7])) {
          int pos = 7;
          while (pos > 0 && (bv[pos - 1] > v || (bv[pos - 1] == v && bj2[pos - 1] > j))) {
            bv[pos] = bv[pos - 1]; bj2[pos] = bj2[pos - 1]; --pos;
          }
          bv[pos] = v; bj2[pos] = j;
        }
      }
    }
    const float *m0 = mx + (size_t)bj2[0] * C_DIM, *m1 = mx + (size_t)bj2[1] * C_DIM;
    const float *m2 = mx + (size_t)bj2[2] * C_DIM, *m3 = mx + (size_t)bj2[3] * C_DIM;
    const float *m4 = mx + (size_t)bj2[4] * C_DIM, *m5 = mx + (size_t)bj2[5] * C_DIM;
    const float *m6 = mx + (size_t)bj2[6] * C_DIM, *m7 = mx + (size_t)bj2[7] * C_DIM;
    const float* xq = x + (size_t)bb * C_DIM * HW + hw0 + t;
    double d0 = 0, d1 = 0, d2 = 0, d3 = 0, d4 = 0, d5 = 0, d6 = 0, d7 = 0;
#pragma unroll 4
    for (int c = 0; c < C_DIM; ++c) {
      const double xv = (double)xq[(size_t)c * HW];
      double dd;
      dd = xv - (double)m0[c]; d0 = fma(dd, dd, d0);
      dd = xv - (double)m1[c]; d1 = fma(dd, dd, d1);
      dd = xv - (double)m2[c]; d2 = fma(dd, dd, d2);
      dd = xv - (double)m3[c]; d3 = fma(dd, dd, d3);
      dd = xv - (double)m4[c]; d4 = fma(dd, dd, d4);
      dd = xv - (double)m5[c]; d5 = fma(dd, dd, d5);
      dd = xv - (double)m6[c]; d6 = fma(dd, dd, d6);
      dd = xv - (double)m7[c]; d7 = fma(dd, dd, d7);
    }
    const double dv[8] = {d0, d1, d2, d3, d4, d5, d6, d7};
    const int    jvv[8] = {bj2[0], bj2[1], bj2[2], bj2[3], bj2[4], bj2[5], bj2[6], bj2[7]};
    int labs[KSEL]; unsigned used = 0;
#pragma unroll
    for (int n = 0; n < KSEL; ++n) {
      double bd = 1e300; int bj = 0x7fffffff; int bk = 0;
#pragma unroll
      for (int k = 0; k < 8; ++k) {
        const bool avail = ((used >> k) & 1u) == 0u;
        if (avail && (dv[k] < bd || (dv[k] == bd && jvv[k] < bj))) {
          bd = dv[k]; bj = jvv[k]; bk = k;
        }
      }
      used |= (1u << bk);
      labs[n] = my[bj];
    }
    int bestLab = NUM_CLASSES, bestCnt = 0;
#pragma unroll
    for (int a = 0; a < KSEL; ++a) {
      int cnt = 0;
#pragma unroll
      for (int b2 = 0; b2 < KSEL; ++b2) cnt += (labs[b2] == labs[a]) ? 1 : 0;
      if (cnt > bestCnt || (cnt == bestCnt && labs[a] < bestLab)) {
        bestCnt = cnt; bestLab = labs[a];
      }
    }
    float* ob = out + (size_t)bb * NUM_CLASSES * HW + hw0 + t;
#pragma unroll
    for (int cls = 0; cls < NUM_CLASSES; ++cls)
      ob[(size_t)cls * HW] = (cls == bestLab) ? 1.0f : 0.0f;   // coalesced per plane
  }
}

// ================= fallback (round-6 kernel, proven): used if ws too small ========
#define FNQB 64
#define FNJB 128
#define FNT 79
#define FXP 264
#define FMP 40
__global__ __launch_bounds__(256, 2) void knn_fb(
    const float* __restrict__ x, const float* __restrict__ mx,
    const int* __restrict__ my, float* __restrict__ out)
{
  __shared__ union {
    struct { ushort xs[FNQB][FXP]; ushort ms[FNJB][FMP]; float mnv[FNJB]; } m;
    struct { float Lv[FNQB][8][KSEL]; int Lj[FNQB][8][KSEL]; } e;
  } sm;
  const int t = threadIdx.x, w = t >> 6, l = t & 63;
  const int wj = w >> 1, wq = w & 1, lr = l & 15, lg = l >> 4;
  const int qflat = blockIdx.x * FNQB, bb = qflat >> 14, hw0 = qflat & (HW - 1);
  const float* xbase = x + (size_t)bb * C_DIM * HW + hw0;
  {
    const int q = t & 63, cpb = t >> 6;
#pragma unroll 8
    for (int k = 0; k < 32; ++k) {
      const int cp = cpb + 4 * k;
      ((uint*)&sm.m.xs[q][0])[cp] =
          pk2(xbase[(size_t)(2 * cp) * HW + q], xbase[(size_t)(2 * cp + 1) * HW + q]);
    }
  }
  float lv[2][KSEL]; int lj[2][KSEL]; float thr[2];
#pragma unroll
  for (int qf = 0; qf < 2; ++qf) {
    thr[qf] = INFV;
#pragma unroll
    for (int e = 0; e < KSEL; ++e) { lv[qf][e] = INFV; lj[qf][e] = 0x7fffffff; }
  }
  const int srow = t >> 1, sh = t & 1;
  for (int jt = 0; jt < FNT; ++jt) {
    const int j0 = jt * FNJB;
    f32x4 acc[4][2];
#pragma unroll
    for (int jf = 0; jf < 4; ++jf)
#pragma unroll
      for (int qf = 0; qf < 2; ++qf) acc[jf][qf] = (f32x4){0.f, 0.f, 0.f, 0.f};
    float np = 0.f;
    for (int ks = 0; ks < 8; ++ks) {
      int jr = j0 + srow; jr = (jr < M_PTS) ? jr : (M_PTS - 1);
      const float4* src = (const float4*)(mx + (size_t)jr * C_DIM + ks * 32 + sh * 16);
      const float4 v0 = src[0], v1 = src[1], v2 = src[2], v3 = src[3];
      __syncthreads();
      uint* dst = (uint*)&sm.m.ms[srow][sh * 16];
      dst[0] = pk2(v0.x, v0.y); dst[1] = pk2(v0.z, v0.w);
      dst[2] = pk2(v1.x, v1.y); dst[3] = pk2(v1.z, v1.w);
      dst[4] = pk2(v2.x, v2.y); dst[5] = pk2(v2.z, v2.w);
      dst[6] = pk2(v3.x, v3.y); dst[7] = pk2(v3.z, v3.w);
      np = fmaf(v0.x, v0.x, np); np = fmaf(v0.y, v0.y, np);
      np = fmaf(v0.z, v0.z, np); np = fmaf(v0.w, v0.w, np);
      np = fmaf(v1.x, v1.x, np); np = fmaf(v1.y, v1.y, np);
      np = fmaf(v1.z, v1.z, np); np = fmaf(v1.w, v1.w, np);
      np = fmaf(v2.x, v2.x, np); np = fmaf(v2.y, v2.y, np);
      np = fmaf(v2.z, v2.z, np); np = fmaf(v2.w, v2.w, np);
      np = fmaf(v3.x, v3.x, np); np = fmaf(v3.y, v3.y, np);
      np = fmaf(v3.z, v3.z, np); np = fmaf(v3.w, v3.w, np);
      if (ks == 7) {
        const float full = np + __shfl_xor(np, 1);
        if (sh == 0) sm.m.mnv[srow] = full;
      }
      __syncthreads();
      const short8 bq0 = *(const short8*)&sm.m.xs[wq * 32 + lr][ks * 32 + 8 * lg];
      const short8 bq1 = *(const short8*)&sm.m.xs[wq * 32 + 16 + lr][ks * 32 + 8 * lg];
#pragma unroll
      for (int jf = 0; jf < 4; ++jf) {
        const short8 af = *(const short8*)&sm.m.ms[wj * 64 + jf * 16 + lr][8 * lg];
        acc[jf][0] = MFMA16(af, bq0, acc[jf][0]);
        acc[jf][1] = MFMA16(af, bq1, acc[jf][1]);
      }
    }
#pragma unroll
    for (int jf = 0; jf < 4; ++jf) {
      const f32x4 mn4 = *(const f32x4*)&sm.m.mnv[wj * 64 + jf * 16 + 4 * lg];
      const int jb = j0 + wj * 64 + jf * 16 + 4 * lg;
#pragma unroll
      for (int qf = 0; qf < 2; ++qf) {
#pragma unroll
        for (int e = 0; e < 4; ++e) {
          const int jg = jb + e;
          const float sc = fmaf(-2.f, acc[jf][qf][e], mn4[e]);
          if (jg < M_PTS && sc < thr[qf]) {
            const float v0 = lv[qf][0], v1 = lv[qf][1], v2 = lv[qf][2], v3 = lv[qf][3];
            const int   i0 = lj[qf][0], i1 = lj[qf][1], i2 = lj[qf][2], i3 = lj[qf][3];
            const bool c0 = sc < v0, c1 = sc < v1, c2 = sc < v2, c3 = sc < v3;
            lv[qf][4] = c3 ? v3 : sc;             lj[qf][4] = c3 ? i3 : jg;
            lv[qf][3] = c3 ? (c2 ? v2 : sc) : v3; lj[qf][3] = c3 ? (c2 ? i2 : jg) : i3;
            lv[qf][2] = c2 ? (c1 ? v1 : sc) : v2; lj[qf][2] = c2 ? (c1 ? i1 : jg) : i2;
            lv[qf][1] = c1 ? (c0 ? v0 : sc) : v1; lj[qf][1] = c1 ? (c0 ? i0 : jg) : i1;
            lv[qf][0] = c0 ? sc : v0;             lj[qf][0] = c0 ? jg : i0;
            thr[qf] = lv[qf][4];
          }
        }
      }
    }
  }
  __syncthreads();
#pragma unroll
  for (int qf = 0; qf < 2; ++qf) {
    const int q = wq * 32 + qf * 16 + lr, s = wj * 4 + lg;
#pragma unroll
    for (int e = 0; e < KSEL; ++e) { sm.e.Lv[q][s][e] = lv[qf][e]; sm.e.Lj[q][s][e] = lj[qf][e]; }
  }
  __syncthreads();
  if (t < FNQB) {
    float bv[8]; int bj2[8];
#pragma unroll
    for (int k = 0; k < 8; ++k) { bv[k] = INFV; bj2[k] = 0x7fffffff; }
    for (int s = 0; s < 8; ++s) {
#pragma unroll
      for (int e = 0; e < KSEL; ++e) {
        const float v = sm.e.Lv[t][s][e]; const int j = sm.e.Lj[t][s][e];
        if (v < bv[7] || (v == bv[7] && j < bj2[7])) {
          int pos = 7;
          while (pos > 0 && (bv[pos - 1] > v || (bv[pos - 1] == v && bj2[pos - 1] > j))) {
            bv[pos] = bv[pos - 1]; bj2[pos] = bj2[pos - 1]; --pos;
          }
          bv[pos] = v; bj2[pos] = j;
        }
      }
    }
    const float *m0 = mx + (size_t)bj2[0] * C_DIM, *m1 = mx + (size_t)bj2[1] * C_DIM;
    const float *m2 = mx + (size_t)bj2[2] * C_DIM, *m3 = mx + (size_t)bj2[3] * C_DIM;
    const float *m4 = mx + (size_t)bj2[4] * C_DIM, *m5 = mx + (size_t)bj2[5] * C_DIM;
    const float *m6 = mx + (size_t)bj2[6] * C_DIM, *m7 = mx + (size_t)bj2[7] * C_DIM;
    const float* xq = xbase + t;
    double d0 = 0, d1 = 0, d2 = 0, d3 = 0, d4 = 0, d5 = 0, d6 = 0, d7 = 0;
#pragma unroll 4
    for (int c = 0; c < C_DIM; ++c) {
      const double xv = (double)xq[(size_t)c * HW];
      double dd;
      dd = xv - (double)m0[c]; d0 = fma(dd, dd, d0);
      dd = xv - (double)m1[c]; d1 = fma(dd, dd, d1);
      dd = xv - (double)m2[c]; d2 = fma(dd, dd, d2);
      dd = xv - (double)m3[c]; d3 = fma(dd, dd, d3);
      dd = xv - (double)m4[c]; d4 = fma(dd, dd, d4);
      dd = xv - (double)m5[c]; d5 = fma(dd, dd, d5);
      dd = xv - (double)m6[c]; d6 = fma(dd, dd, d6);
      dd = xv - (double)m7[c]; d7 = fma(dd, dd, d7);
    }
    const double dv[8] = {d0, d1, d2, d3, d4, d5, d6, d7};
    const int jvv[8] = {bj2[0], bj2[1], bj2[2], bj2[3], bj2[4], bj2[5], bj2[6], bj2[7]};
    int labs[KSEL]; unsigned used = 0;
#pragma unroll
    for (int n = 0; n < KSEL; ++n) {
      double bd = 1e300; int bj = 0x7fffffff; int bk = 0;
#pragma unroll
      for (int k = 0; k < 8; ++k) {
        const bool avail = ((used >> k) & 1u) == 0u;
        if (avail && (dv[k] < bd || (dv[k] == bd && jvv[k] < bj))) {
          bd = dv[k]; bj = jvv[k]; bk = k;
        }
      }
      used |= (1u << bk);
      labs[n] = my[bj];
    }
    int bestLab = NUM_CLASSES, bestCnt = 0;
#pragma unroll
    for (int a = 0; a < KSEL; ++a) {
      int cnt = 0;
#pragma unroll
      for (int b2 = 0; b2 < KSEL; ++b2) cnt += (labs[b2] == labs[a]) ? 1 : 0;
      if (cnt > bestCnt || (cnt == bestCnt && labs[a] < bestLab)) { bestCnt = cnt; bestLab = labs[a]; }
    }
    float* ob = out + (size_t)bb * NUM_CLASSES * HW + hw0 + t;
#pragma unroll
    for (int cls = 0; cls < NUM_CLASSES; ++cls)
      ob[(size_t)cls * HW] = (cls == bestLab) ? 1.0f : 0.0f;
  }
}

extern "C" void kernel_launch(void* const* d_in, const int* in_sizes, int n_in,
                              void* d_out, int out_size, void* d_ws, size_t ws_size,
                              hipStream_t stream) {
  (void)in_sizes; (void)n_in; (void)out_size;
  const float* x  = (const float*)d_in[0];
  const float* mx = (const float*)d_in[2];   // d_in[1] (y) unused by reference
  const int*   my = (const int*)d_in[3];
  float* out = (float*)d_out;
  if (ws_size >= (size_t)WS_TOTAL) {
    float*  mn = (float*)((char*)d_ws + WS_MN_OFF);
    ushort* mw = (ushort*)((char*)d_ws + WS_MW_OFF);
    ushort* xb = (ushort*)((char*)d_ws + WS_XB_OFF);
    conv_m<<<MPAD / 64, 256, 0, stream>>>(mx, mw, mn);
    conv_x<<<32768 / 64, 256, 0, stream>>>(x, xb);
    knn_big<<<32768 / NQB, 512, 0, stream>>>(x, mx, mw, mn, xb, my, out);
  } else {
    knn_fb<<<32768 / FNQB, 256, 0, stream>>>(x, mx, my, out);
  }
}